// Round 1
// baseline (131.554 us; speedup 1.0000x reference)
//
#include <hip/hip_runtime.h>

// Problem shapes (fixed by setup_inputs):
//   x:        [T=16, B=16, C=256, H=32, W=32]  f32   (67,108,864 elems)
//   condition:[T=16, B=16, Cc=256]             f32
//   W:        [2C=512, Cc=256]                 f32
//   b:        [512]                            f32
//   out = (gamma+1)*x + beta,  gamma/beta from spikes @ W^T + b

#define T_STEPS 16
#define B_SZ    16
#define C_SZ    256
#define CC_SZ   256
#define D_SZ    512          // 2*C
#define HW      1024         // 32*32

// ---------------------------------------------------------------------------
// Kernel 1: hard-reset LIF over condition [T, B*Cc] -> spikes (0/1 floats)
// One thread per (b,cc) chain; sequential over T (recurrence).
// Matches reference arithmetic: v += (x - v)/2 ; s = (v-1 >= 0); v = (1-s)*v
// ---------------------------------------------------------------------------
__global__ void lif_kernel(const float* __restrict__ cond,
                           float* __restrict__ spikes, int bcc)
{
    int idx = blockIdx.x * blockDim.x + threadIdx.x;
    if (idx >= bcc) return;
    float v = 0.0f;
#pragma unroll
    for (int t = 0; t < T_STEPS; ++t) {
        float x = cond[t * bcc + idx];
        v = v + (x - v) * 0.5f;               // TAU = 2 (exact /2)
        float s = ((v - 1.0f) >= 0.0f) ? 1.0f : 0.0f;
        spikes[t * bcc + idx] = s;
        v = (s != 0.0f) ? 0.0f : v;           // hard reset, V_RESET = 0
    }
}

// ---------------------------------------------------------------------------
// Kernel 2: params[tb][d] = sum_c spikes[tb][c] * W[d][c] + bias[d]
// One block (512 threads) per tb row; spikes row staged in LDS; W rows read
// as float4 (W is 512 KB -> L2 resident after first block touches it).
// ---------------------------------------------------------------------------
__global__ void film_params_kernel(const float* __restrict__ spikes,
                                   const float* __restrict__ W,
                                   const float* __restrict__ bias,
                                   float* __restrict__ params)
{
    __shared__ float srow[CC_SZ];
    const int tb = blockIdx.x;
    const int d  = threadIdx.x;           // 0..511
    if (d < CC_SZ) srow[d] = spikes[tb * CC_SZ + d];
    __syncthreads();

    const float4* Wrow = reinterpret_cast<const float4*>(W + (size_t)d * CC_SZ);
    float acc = 0.0f;
#pragma unroll 8
    for (int c4 = 0; c4 < CC_SZ / 4; ++c4) {
        float4 w = Wrow[c4];
        acc += w.x * srow[c4 * 4 + 0];
        acc += w.y * srow[c4 * 4 + 1];
        acc += w.z * srow[c4 * 4 + 2];
        acc += w.w * srow[c4 * 4 + 3];
    }
    params[tb * D_SZ + d] = acc + bias[d];
}

// ---------------------------------------------------------------------------
// Kernel 3: out[i] = (gamma+1)*x[i] + beta   (the 512 MB HBM-bound pass)
// float4 grid-stride. Each float4 lies within one (t,b,c) slice (HW=1024).
//   slice s = elem/1024 = i4 >> 8 ;  c = s & 255 ; tb = s >> 8
// ---------------------------------------------------------------------------
__global__ void film_apply_kernel(const float* __restrict__ x,
                                  const float* __restrict__ params,
                                  float* __restrict__ out, long n4)
{
    long i = blockIdx.x * (long)blockDim.x + threadIdx.x;
    const long stride = (long)gridDim.x * blockDim.x;
    const float4* __restrict__ x4 = reinterpret_cast<const float4*>(x);
    float4* __restrict__ o4 = reinterpret_cast<float4*>(out);

    for (; i < n4; i += stride) {
        long s  = i >> 8;                  // (i*4)/1024
        int  c  = (int)(s & (C_SZ - 1));
        long tb = s >> 8;                  // s / C
        const float* p = params + tb * D_SZ;
        float g  = p[c] + 1.0f;            // gamma + 1
        float be = p[c + C_SZ];            // beta
        float4 v = x4[i];
        float4 r;
        r.x = g * v.x + be;
        r.y = g * v.y + be;
        r.z = g * v.z + be;
        r.w = g * v.w + be;
        o4[i] = r;
    }
}

// ---------------------------------------------------------------------------
extern "C" void kernel_launch(void* const* d_in, const int* in_sizes, int n_in,
                              void* d_out, int out_size, void* d_ws, size_t ws_size,
                              hipStream_t stream)
{
    const float* x    = (const float*)d_in[0];
    const float* cond = (const float*)d_in[1];
    const float* W    = (const float*)d_in[2];
    const float* bias = (const float*)d_in[3];
    float* out = (float*)d_out;

    // workspace layout: spikes [T*B*Cc] then params [T*B*2C]
    float* spikes = (float*)d_ws;                          // 65536 f32 = 256 KB
    float* params = spikes + T_STEPS * B_SZ * CC_SZ;       // 131072 f32 = 512 KB

    // K1: LIF — 4096 chains
    {
        int bcc = B_SZ * CC_SZ;                            // 4096
        lif_kernel<<<(bcc + 255) / 256, 256, 0, stream>>>(cond, spikes, bcc);
    }
    // K2: params GEMV — 256 rows × 512 outputs
    {
        film_params_kernel<<<T_STEPS * B_SZ, D_SZ, 0, stream>>>(spikes, W, bias, params);
    }
    // K3: FiLM apply — 67M f32, float4 grid-stride
    {
        long n4 = (long)out_size / 4;                      // 16,777,216
        film_apply_kernel<<<2048, 256, 0, stream>>>(x, params, out, n4);
    }
}

// Round 2
// 114.309 us; speedup vs baseline: 1.1509x; 1.1509x over previous
//
#include <hip/hip_runtime.h>

// Fused SNN-FiLM:
//   x:        [T=16, B=16, C=256, H=32, W=32]  f32  (67,108,864 elems, 256 MB)
//   condition:[T=16, B=16, Cc=256]             f32  (256 KB)
//   W:        [2C=512, Cc=256]                 f32  (512 KB)
//   b:        [512]                            f32
//   out = (gamma+1)*x + beta
//
// Single kernel. Each block owns 32 (t,b,c) slices (32*1024 f32 = 128 KB of x).
// Prologue (per block, redundant but cheap, all operands L2-resident):
//   1. LIF recurrence for batch b, steps 0..t, 256 chains (1 thread/chain)
//   2. 64 dot products (gamma/beta for its 32 c values), 4 threads/row
// Main loop: pure streaming FMA, gamma/beta from LDS (no global param loads).

#define T_STEPS 16
#define B_SZ    16
#define C_SZ    256
#define CC_SZ   256
#define HW      1024
#define SLICES  32            // c-values (slices) per block
#define THREADS 256

__global__ __launch_bounds__(THREADS, 8)
void film_fused_kernel(const float* __restrict__ x,
                       const float* __restrict__ cond,
                       const float* __restrict__ W,
                       const float* __restrict__ bias,
                       float* __restrict__ out)
{
    __shared__ float s_spk[CC_SZ];     // spikes[t, b, :]
    __shared__ float s_part[THREADS];  // dot partials
    __shared__ float s_g[SLICES];      // gamma + 1
    __shared__ float s_b[SLICES];      // beta

    const int bid   = blockIdx.x;          // 0..2047
    const int tb    = bid >> 3;            // 0..255  == t*16 + b
    const int t     = tb >> 4;
    const int b     = tb & (B_SZ - 1);
    const int cbase = (bid & 7) * SLICES;
    const int tid   = threadIdx.x;

    // ---- issue x prefetch for first 4 slices BEFORE the prologue ----------
    const size_t x_base = ((size_t)tb * C_SZ + cbase) * HW;   // element offset
    const float4* __restrict__ x4 = reinterpret_cast<const float4*>(x + x_base);
    float4*       __restrict__ o4 = reinterpret_cast<float4*>(out + x_base);
    float4 pf0 = x4[0 * 256 + tid];
    float4 pf1 = x4[1 * 256 + tid];
    float4 pf2 = x4[2 * 256 + tid];
    float4 pf3 = x4[3 * 256 + tid];

    // ---- LIF recurrence: chain cc = tid, steps 0..t ------------------------
    {
        float v = 0.0f, s = 0.0f;
        const float* cp = cond + (size_t)b * CC_SZ + tid;     // cond[tt, b, cc]
        for (int tt = 0; tt <= t; ++tt) {
            float xv = cp[(size_t)tt * (B_SZ * CC_SZ)];
            v = v + (xv - v) * 0.5f;                          // charge (TAU=2)
            s = ((v - 1.0f) >= 0.0f) ? 1.0f : 0.0f;           // fire
            v = (s != 0.0f) ? 0.0f : v;                       // hard reset
        }
        s_spk[tid] = s;                                       // spike at step t
    }
    __syncthreads();

    // ---- params: 64 rows (32 gamma, 32 beta), 4 threads per row ------------
    {
        const int r = tid >> 2;                               // 0..63
        const int q = tid & 3;                                // quarter of K
        const int d = (r < 32) ? (cbase + r) : (C_SZ + cbase + (r - 32));
        const float4* Wr = reinterpret_cast<const float4*>(W + (size_t)d * CC_SZ)
                           + q * 16;
        const float* sp = s_spk + q * 64;
        float acc = 0.0f;
#pragma unroll
        for (int k = 0; k < 16; ++k) {
            float4 w = Wr[k];
            acc += w.x * sp[k * 4 + 0];
            acc += w.y * sp[k * 4 + 1];
            acc += w.z * sp[k * 4 + 2];
            acc += w.w * sp[k * 4 + 3];
        }
        s_part[tid] = acc;
    }
    __syncthreads();
    if (tid < 64) {
        const int r = tid;
        const int d = (r < 32) ? (cbase + r) : (C_SZ + cbase + (r - 32));
        float val = s_part[4 * r] + s_part[4 * r + 1]
                  + s_part[4 * r + 2] + s_part[4 * r + 3] + bias[d];
        if (r < 32) s_g[r] = val + 1.0f;   // gamma + 1
        else        s_b[r - 32] = val;     // beta
    }
    __syncthreads();

    // ---- apply: 32 slices, one float4 per thread per slice -----------------
    {
        float4 r;
        float g, be;
        g = s_g[0]; be = s_b[0];
        r.x = fmaf(g, pf0.x, be); r.y = fmaf(g, pf0.y, be);
        r.z = fmaf(g, pf0.z, be); r.w = fmaf(g, pf0.w, be);
        o4[0 * 256 + tid] = r;
        g = s_g[1]; be = s_b[1];
        r.x = fmaf(g, pf1.x, be); r.y = fmaf(g, pf1.y, be);
        r.z = fmaf(g, pf1.z, be); r.w = fmaf(g, pf1.w, be);
        o4[1 * 256 + tid] = r;
        g = s_g[2]; be = s_b[2];
        r.x = fmaf(g, pf2.x, be); r.y = fmaf(g, pf2.y, be);
        r.z = fmaf(g, pf2.z, be); r.w = fmaf(g, pf2.w, be);
        o4[2 * 256 + tid] = r;
        g = s_g[3]; be = s_b[3];
        r.x = fmaf(g, pf3.x, be); r.y = fmaf(g, pf3.y, be);
        r.z = fmaf(g, pf3.z, be); r.w = fmaf(g, pf3.w, be);
        o4[3 * 256 + tid] = r;

#pragma unroll 4
        for (int sidx = 4; sidx < SLICES; ++sidx) {
            float4 v = x4[(size_t)sidx * 256 + tid];
            float gg = s_g[sidx], bb = s_b[sidx];
            float4 rr;
            rr.x = fmaf(gg, v.x, bb);
            rr.y = fmaf(gg, v.y, bb);
            rr.z = fmaf(gg, v.z, bb);
            rr.w = fmaf(gg, v.w, bb);
            o4[(size_t)sidx * 256 + tid] = rr;
        }
    }
}

extern "C" void kernel_launch(void* const* d_in, const int* in_sizes, int n_in,
                              void* d_out, int out_size, void* d_ws, size_t ws_size,
                              hipStream_t stream)
{
    const float* x    = (const float*)d_in[0];
    const float* cond = (const float*)d_in[1];
    const float* W    = (const float*)d_in[2];
    const float* bias = (const float*)d_in[3];
    float* out = (float*)d_out;

    // total slices = T*B*C = 65536; 32 per block -> 2048 blocks (8/CU, full
    // 32-wave residency on 256 CUs)
    film_fused_kernel<<<2048, THREADS, 0, stream>>>(x, cond, W, bias, out);
}

// Round 3
// 105.567 us; speedup vs baseline: 1.2462x; 1.0828x over previous
//
#include <hip/hip_runtime.h>

// Fused SNN-FiLM, v3:
//   x:        [T=16, B=16, C=256, H=32, W=32]  f32  (256 MB)
//   condition:[T=16, B=16, Cc=256]             f32  (256 KB, L2-resident)
//   W:        [2C=512, Cc=256]                 f32  (512 KB, L2-resident)
//   b:        [512]                            f32
//   out = (gamma+1)*x + beta
//
// One kernel, 2048 blocks x 256 threads, 8 blocks/CU (full residency).
// Block prologue (redundant per block, all L2-resident):
//   - LIF: 16 independent cond loads -> register recurrence (no serial
//     load-latency chain)
//   - 64 dot products, 4 threads/row, shfl_xor quad reduction (no LDS
//     partials, 2 syncthreads total)
// Main loop: 4+4 double-buffered nontemporal float4 stream.

#define T_STEPS 16
#define B_SZ    16
#define C_SZ    256
#define CC_SZ   256
#define HW      1024
#define SLICES  32
#define THREADS 256

typedef float f4 __attribute__((ext_vector_type(4)));

__global__ __launch_bounds__(THREADS, 8)
void film_fused_kernel(const float* __restrict__ x,
                       const float* __restrict__ cond,
                       const float* __restrict__ W,
                       const float* __restrict__ bias,
                       float* __restrict__ out)
{
    __shared__ float s_spk[CC_SZ];     // spikes[t, b, :]
    __shared__ float s_g[SLICES];      // gamma + 1
    __shared__ float s_b[SLICES];      // beta

    const int bid   = blockIdx.x;          // 0..2047
    const int tb    = bid >> 3;            // t*16 + b
    const int t     = tb >> 4;
    const int b     = tb & (B_SZ - 1);
    const int cbase = (bid & 7) * SLICES;
    const int tid   = threadIdx.x;

    const size_t x_base = ((size_t)tb * C_SZ + cbase) * HW;
    const f4* __restrict__ x4 = reinterpret_cast<const f4*>(x + x_base);
    f4*       __restrict__ o4 = reinterpret_cast<f4*>(out + x_base);

    // ---- prefetch first 4 slices (keeps HBM busy through the prologue) ----
    f4 pf0 = __builtin_nontemporal_load(&x4[0 * 256 + tid]);
    f4 pf1 = __builtin_nontemporal_load(&x4[1 * 256 + tid]);
    f4 pf2 = __builtin_nontemporal_load(&x4[2 * 256 + tid]);
    f4 pf3 = __builtin_nontemporal_load(&x4[3 * 256 + tid]);

    // ---- LIF: all 16 cond loads issued independently, then reg recurrence --
    {
        const float* cp = cond + (size_t)b * CC_SZ + tid;
        float cv[T_STEPS];
#pragma unroll
        for (int tt = 0; tt < T_STEPS; ++tt)
            cv[tt] = cp[(size_t)tt * (B_SZ * CC_SZ)];
        float v = 0.0f, s = 0.0f;
#pragma unroll
        for (int tt = 0; tt < T_STEPS; ++tt) {
            if (tt <= t) {                                // wave-uniform guard
                v = v + (cv[tt] - v) * 0.5f;              // charge (TAU=2)
                s = (v >= 1.0f) ? 1.0f : 0.0f;            // fire
                v = (s != 0.0f) ? 0.0f : v;               // hard reset
            }
        }
        s_spk[tid] = s;                                   // spike at step t
    }
    __syncthreads();

    // ---- params: 64 rows, 4 threads/row, shfl quad-reduce ------------------
    {
        const int r = tid >> 2;                           // 0..63
        const int q = tid & 3;                            // K-quarter
        const int d = (r < 32) ? (cbase + r) : (C_SZ + cbase + (r - 32));
        const f4* Wr = reinterpret_cast<const f4*>(W + (size_t)d * CC_SZ)
                       + q * 16;
        const float* sp = s_spk + q * 64;
        float acc = 0.0f;
#pragma unroll
        for (int k = 0; k < 16; ++k) {
            f4 w = Wr[k];
            acc += w.x * sp[4 * k + 0];
            acc += w.y * sp[4 * k + 1];
            acc += w.z * sp[4 * k + 2];
            acc += w.w * sp[4 * k + 3];
        }
        acc += __shfl_xor(acc, 1);
        acc += __shfl_xor(acc, 2);
        if (q == 0) {
            float val = acc + bias[d];
            if (r < 32) s_g[r] = val + 1.0f;              // gamma + 1
            else        s_b[r - 32] = val;                // beta
        }
    }
    __syncthreads();

    // ---- streaming: 4+4 double-buffered nontemporal float4 stream ----------
#define APPLY_STORE(cc, so)                                                   \
    {                                                                         \
        float g_ = s_g[so], b_ = s_b[so];                                     \
        f4 r_;                                                                \
        r_.x = fmaf(g_, (cc).x, b_);                                          \
        r_.y = fmaf(g_, (cc).y, b_);                                          \
        r_.z = fmaf(g_, (cc).z, b_);                                          \
        r_.w = fmaf(g_, (cc).w, b_);                                          \
        __builtin_nontemporal_store(r_, &o4[(size_t)(so) * 256 + tid]);       \
    }

    f4 c0 = pf0, c1 = pf1, c2 = pf2, c3 = pf3;
    int sidx = 0;
    for (; sidx + 4 < SLICES; sidx += 4) {
        f4 n0 = __builtin_nontemporal_load(&x4[(size_t)(sidx + 4) * 256 + tid]);
        f4 n1 = __builtin_nontemporal_load(&x4[(size_t)(sidx + 5) * 256 + tid]);
        f4 n2 = __builtin_nontemporal_load(&x4[(size_t)(sidx + 6) * 256 + tid]);
        f4 n3 = __builtin_nontemporal_load(&x4[(size_t)(sidx + 7) * 256 + tid]);
        APPLY_STORE(c0, sidx + 0);
        APPLY_STORE(c1, sidx + 1);
        APPLY_STORE(c2, sidx + 2);
        APPLY_STORE(c3, sidx + 3);
        c0 = n0; c1 = n1; c2 = n2; c3 = n3;
    }
    APPLY_STORE(c0, sidx + 0);
    APPLY_STORE(c1, sidx + 1);
    APPLY_STORE(c2, sidx + 2);
    APPLY_STORE(c3, sidx + 3);
#undef APPLY_STORE
}

extern "C" void kernel_launch(void* const* d_in, const int* in_sizes, int n_in,
                              void* d_out, int out_size, void* d_ws, size_t ws_size,
                              hipStream_t stream)
{
    const float* x    = (const float*)d_in[0];
    const float* cond = (const float*)d_in[1];
    const float* W    = (const float*)d_in[2];
    const float* bias = (const float*)d_in[3];
    float* out = (float*)d_out;

    film_fused_kernel<<<2048, THREADS, 0, stream>>>(x, cond, W, bias, out);
}

// Round 4
// 99.060 us; speedup vs baseline: 1.3280x; 1.0657x over previous
//
#include <hip/hip_runtime.h>

// Fused SNN-FiLM, v4 — wave-owned slices, SGPR gamma/beta, LDS-free hot loop.
//   x:        [T=16, B=16, C=256, H=32, W=32]  f32  (256 MB)
//   condition:[T=16, B=16, Cc=256]             f32  (256 KB, L2-resident)
//   W:        [2C=512, Cc=256]                 f32  (512 KB, L2-resident)
//   b:        [512]                            f32
//   out = (gamma+1)*x + beta
//
// 2048 blocks x 256 threads, 8 blocks/CU. Block owns 32 slices (128 KB);
// wave w owns slices [8w, 8w+8) (32 KB contiguous). Prologue computes the
// 32 gamma/beta pairs (LIF + dot products, all L2-resident operands); each
// wave then lifts its 8 pairs into SGPRs and streams with a fully-unrolled,
// statically-indexed, 2-deep pipelined float4 loop — no LDS, no dynamic
// indexing, nontemporal on both streams.

#define T_STEPS 16
#define B_SZ    16
#define C_SZ    256
#define CC_SZ   256
#define HW      1024
#define SLICES  32
#define THREADS 256
#define WSLICES 8            // slices per wave

typedef float f4 __attribute__((ext_vector_type(4)));

__device__ __forceinline__ float rfl(float v) {
    union { float f; int i; } u;
    u.f = v;
    u.i = __builtin_amdgcn_readfirstlane(u.i);
    return u.f;
}

__global__ __launch_bounds__(THREADS, 8)
void film_fused_kernel(const float* __restrict__ x,
                       const float* __restrict__ cond,
                       const float* __restrict__ W,
                       const float* __restrict__ bias,
                       float* __restrict__ out)
{
    __shared__ float s_spk[CC_SZ];     // spikes[t, b, :]
    __shared__ float s_g[SLICES];      // gamma + 1
    __shared__ float s_b[SLICES];      // beta

    const int bid   = blockIdx.x;          // 0..2047
    const int tb    = bid >> 3;            // t*16 + b
    const int t     = tb >> 4;
    const int b     = tb & (B_SZ - 1);
    const int cbase = (bid & 7) * SLICES;
    const int tid   = threadIdx.x;
    const int wid   = tid >> 6;            // wave 0..3
    const int lane  = tid & 63;

    // wave-local base: block's 32 slices, wave takes 8 (32 KB contiguous)
    const size_t x_base = ((size_t)tb * C_SZ + cbase + wid * WSLICES) * HW;
    const f4* __restrict__ xw = reinterpret_cast<const f4*>(x + x_base);
    f4*       __restrict__ ow = reinterpret_cast<f4*>(out + x_base);

    // ---- prefetch wave's slice 0 (keeps HBM busy through the prologue) ----
    f4 c0 = __builtin_nontemporal_load(&xw[0 * 64 + lane]);
    f4 c1 = __builtin_nontemporal_load(&xw[1 * 64 + lane]);
    f4 c2 = __builtin_nontemporal_load(&xw[2 * 64 + lane]);
    f4 c3 = __builtin_nontemporal_load(&xw[3 * 64 + lane]);

    // ---- LIF: 16 independent cond loads -> register recurrence ------------
    {
        const float* cp = cond + (size_t)b * CC_SZ + tid;
        float cv[T_STEPS];
#pragma unroll
        for (int tt = 0; tt < T_STEPS; ++tt)
            cv[tt] = cp[(size_t)tt * (B_SZ * CC_SZ)];
        float v = 0.0f, s = 0.0f;
#pragma unroll
        for (int tt = 0; tt < T_STEPS; ++tt) {
            if (tt <= t) {                                // wave-uniform guard
                v = v + (cv[tt] - v) * 0.5f;              // charge (TAU=2)
                s = (v >= 1.0f) ? 1.0f : 0.0f;            // fire
                v = (s != 0.0f) ? 0.0f : v;               // hard reset
            }
        }
        s_spk[tid] = s;                                   // spike at step t
    }
    __syncthreads();

    // ---- params: 64 rows, 4 threads/row, shfl quad-reduce ------------------
    {
        const int r = tid >> 2;                           // 0..63
        const int q = tid & 3;                            // K-quarter
        const int d = (r < 32) ? (cbase + r) : (C_SZ + cbase + (r - 32));
        const f4* Wr = reinterpret_cast<const f4*>(W + (size_t)d * CC_SZ)
                       + q * 16;
        const float* sp = s_spk + q * 64;
        float acc = 0.0f;
#pragma unroll
        for (int k = 0; k < 16; ++k) {
            f4 w = Wr[k];
            acc += w.x * sp[4 * k + 0];
            acc += w.y * sp[4 * k + 1];
            acc += w.z * sp[4 * k + 2];
            acc += w.w * sp[4 * k + 3];
        }
        acc += __shfl_xor(acc, 1);
        acc += __shfl_xor(acc, 2);
        if (q == 0) {
            float val = acc + bias[d];
            if (r < 32) s_g[r] = val + 1.0f;              // gamma + 1
            else        s_b[r - 32] = val;                // beta
        }
    }
    __syncthreads();

    // ---- lift this wave's 8 gamma/beta pairs into SGPRs --------------------
    float g[WSLICES], be[WSLICES];
#pragma unroll
    for (int i = 0; i < WSLICES; ++i) {
        g[i]  = rfl(s_g[wid * WSLICES + i]);
        be[i] = rfl(s_b[wid * WSLICES + i]);
    }

    // ---- steady state: 8 slices, fully unrolled, 2-deep pipeline, no LDS ---
#pragma unroll
    for (int s = 0; s < WSLICES; ++s) {
        f4 n0, n1, n2, n3;
        if (s + 1 < WSLICES) {
            n0 = __builtin_nontemporal_load(&xw[(s + 1) * 256 + 0 * 64 + lane]);
            n1 = __builtin_nontemporal_load(&xw[(s + 1) * 256 + 1 * 64 + lane]);
            n2 = __builtin_nontemporal_load(&xw[(s + 1) * 256 + 2 * 64 + lane]);
            n3 = __builtin_nontemporal_load(&xw[(s + 1) * 256 + 3 * 64 + lane]);
        }
        f4 r0, r1, r2, r3;
        r0.x = fmaf(g[s], c0.x, be[s]); r0.y = fmaf(g[s], c0.y, be[s]);
        r0.z = fmaf(g[s], c0.z, be[s]); r0.w = fmaf(g[s], c0.w, be[s]);
        r1.x = fmaf(g[s], c1.x, be[s]); r1.y = fmaf(g[s], c1.y, be[s]);
        r1.z = fmaf(g[s], c1.z, be[s]); r1.w = fmaf(g[s], c1.w, be[s]);
        r2.x = fmaf(g[s], c2.x, be[s]); r2.y = fmaf(g[s], c2.y, be[s]);
        r2.z = fmaf(g[s], c2.z, be[s]); r2.w = fmaf(g[s], c2.w, be[s]);
        r3.x = fmaf(g[s], c3.x, be[s]); r3.y = fmaf(g[s], c3.y, be[s]);
        r3.z = fmaf(g[s], c3.z, be[s]); r3.w = fmaf(g[s], c3.w, be[s]);
        __builtin_nontemporal_store(r0, &ow[s * 256 + 0 * 64 + lane]);
        __builtin_nontemporal_store(r1, &ow[s * 256 + 1 * 64 + lane]);
        __builtin_nontemporal_store(r2, &ow[s * 256 + 2 * 64 + lane]);
        __builtin_nontemporal_store(r3, &ow[s * 256 + 3 * 64 + lane]);
        c0 = n0; c1 = n1; c2 = n2; c3 = n3;
    }
}

extern "C" void kernel_launch(void* const* d_in, const int* in_sizes, int n_in,
                              void* d_out, int out_size, void* d_ws, size_t ws_size,
                              hipStream_t stream)
{
    const float* x    = (const float*)d_in[0];
    const float* cond = (const float*)d_in[1];
    const float* W    = (const float*)d_in[2];
    const float* bias = (const float*)d_in[3];
    float* out = (float*)d_out;

    film_fused_kernel<<<2048, THREADS, 0, stream>>>(x, cond, W, bias, out);
}

// Round 5
// 98.447 us; speedup vs baseline: 1.3363x; 1.0062x over previous
//
#include <hip/hip_runtime.h>

// SNN-FiLM v5 — two-kernel: tiny param kernel + pure HBM streamer.
//   x:        [T=16, B=16, C=256, H=32, W=32]  f32  (256 MB)
//   condition:[T=16, B=16, Cc=256]             f32
//   W:        [2C=512, Cc=256]                 f32
//   b:        [512]                            f32
//   out = (gamma+1)*x + beta
//
// Kernel A: params[t*16+b][d] ; gamma rows stored as gamma+1+bias, beta rows
//   as beta+bias. Grid (b,dg,tg) = 16*8*4 = 512 blocks x 256 thr. LIF chain
//   is sequential in t, so ONE pass yields spikes for all 16 steps; each
//   block records its 4 t's. W tile per block = 64 rows (64 KB), reused
//   across 4 t's -> 32 MB total L2 W-traffic (vs 128 MB fused).
// Kernel B: 2048 blocks x 256 thr, 8/CU. Wave owns 8 slices (32 KB). Params
//   fetched via wave-uniform (scalar) loads -> lgkmcnt, decoupled from the
//   vmem FIFO so the x-prefetch never blocks them. Fully unrolled 2-ahead
//   float4 pipeline, nontemporal, no LDS, no barriers.

#define T_STEPS 16
#define B_SZ    16
#define C_SZ    256
#define CC_SZ   256
#define HW      1024
#define THREADS 256

typedef float f4 __attribute__((ext_vector_type(4)));

__device__ __forceinline__ float qreduce(float v) {   // sum over 4-lane group
    v += __shfl_xor(v, 1);
    v += __shfl_xor(v, 2);
    return v;
}

// ---------------------------------------------------------------------------
// Kernel A — params
// ---------------------------------------------------------------------------
__global__ __launch_bounds__(THREADS)
void params_kernel(const float* __restrict__ cond,
                   const float* __restrict__ W,
                   const float* __restrict__ bias,
                   float* __restrict__ params)
{
    __shared__ f4 s_spk[CC_SZ];        // [cc] -> spikes for t = tg*4 .. tg*4+3

    const int bid = blockIdx.x;        // 0..511
    const int tg  = bid & 3;           // t-group (4 t's)
    const int dg  = (bid >> 2) & 7;    // d-group (64 rows)
    const int b   = bid >> 5;          // batch
    const int tid = threadIdx.x;

    // ---- LIF: one full 16-step chain per cc, record this block's 4 t's ----
    {
        const float* cp = cond + (size_t)b * CC_SZ + tid;
        float v = 0.0f;
        f4 rec = {0.f, 0.f, 0.f, 0.f};
#pragma unroll
        for (int t = 0; t < T_STEPS; ++t) {
            float xv = cp[(size_t)t * (B_SZ * CC_SZ)];
            v = v + (xv - v) * 0.5f;                  // charge (TAU=2)
            float s = (v >= 1.0f) ? 1.0f : 0.0f;      // fire
            v = (s != 0.0f) ? 0.0f : v;               // hard reset
            const bool mine = ((t >> 2) == tg);       // runtime pred, static dst
            if ((t & 3) == 0) rec.x = mine ? s : rec.x;
            if ((t & 3) == 1) rec.y = mine ? s : rec.y;
            if ((t & 3) == 2) rec.z = mine ? s : rec.z;
            if ((t & 3) == 3) rec.w = mine ? s : rec.w;
        }
        s_spk[tid] = rec;
    }
    __syncthreads();

    // ---- dots: row r = tid>>2 (64 rows), K-quarter q = tid&3, 4 t's --------
    {
        const int r = tid >> 2;
        const int q = tid & 3;
        const int d = dg * 64 + r;                    // 0..511
        const f4* Wr = reinterpret_cast<const f4*>(W + (size_t)d * CC_SZ)
                       + q * 16;
        const f4* sp = s_spk + q * 64;
        f4 acc = {0.f, 0.f, 0.f, 0.f};                // acc[j] for t = tg*4+j
#pragma unroll
        for (int k = 0; k < 16; ++k) {
            f4 w  = Wr[k];
            f4 s0 = sp[4 * k + 0];
            f4 s1 = sp[4 * k + 1];
            f4 s2 = sp[4 * k + 2];
            f4 s3 = sp[4 * k + 3];
            acc += w.x * s0 + w.y * s1 + w.z * s2 + w.w * s3;
        }
        acc.x = qreduce(acc.x);
        acc.y = qreduce(acc.y);
        acc.z = qreduce(acc.z);
        acc.w = qreduce(acc.w);
        if (q == 0) {
            const float add = bias[d] + ((d < C_SZ) ? 1.0f : 0.0f); // bake +1
            float vals[4] = {acc.x + add, acc.y + add, acc.z + add, acc.w + add};
#pragma unroll
            for (int j = 0; j < 4; ++j) {
                const int t = tg * 4 + j;
                params[((size_t)t * B_SZ + b) * 512 + d] = vals[j];
            }
        }
    }
}

// ---------------------------------------------------------------------------
// Kernel B — pure streamer
// ---------------------------------------------------------------------------
__global__ __launch_bounds__(THREADS, 8)
void stream_kernel(const float* __restrict__ x,
                   const float* __restrict__ params,
                   float* __restrict__ out)
{
    const int bid  = blockIdx.x;           // 0..2047
    const int tb   = bid >> 3;             // t*16 + b
    const int cb   = (bid & 7) * 32;       // block's c base
    const int tid  = threadIdx.x;
    const int wid  = __builtin_amdgcn_readfirstlane(tid >> 6);  // wave 0..3
    const int lane = tid & 63;

    const size_t base = ((size_t)tb * C_SZ + cb + wid * 8) * HW;
    const f4* __restrict__ xw = reinterpret_cast<const f4*>(x + base);
    f4*       __restrict__ ow = reinterpret_cast<f4*>(out + base);

    // ---- prefetch slices 0,1 (vmcnt FIFO head) -----------------------------
    f4 buf[8][4];
#pragma unroll
    for (int i = 0; i < 4; ++i)
        buf[0][i] = __builtin_nontemporal_load(&xw[0 * 256 + i * 64 + lane]);
#pragma unroll
    for (int i = 0; i < 4; ++i)
        buf[1][i] = __builtin_nontemporal_load(&xw[1 * 256 + i * 64 + lane]);

    // ---- gamma/beta: wave-uniform addresses -> scalar loads (lgkmcnt) ------
    const float* pg = params + (size_t)tb * 512 + cb + wid * 8;  // gamma+1
    const float* pb = pg + C_SZ;                                 // beta
    float g[8], be[8];
#pragma unroll
    for (int i = 0; i < 8; ++i) { g[i] = pg[i]; be[i] = pb[i]; }

    // ---- fully-unrolled 2-ahead pipeline ------------------------------------
#pragma unroll
    for (int s = 0; s < 8; ++s) {
        if (s + 2 < 8) {
#pragma unroll
            for (int i = 0; i < 4; ++i)
                buf[s + 2][i] = __builtin_nontemporal_load(
                    &xw[(size_t)(s + 2) * 256 + i * 64 + lane]);
        }
#pragma unroll
        for (int i = 0; i < 4; ++i) {
            f4 v = buf[s][i];
            f4 r;
            r.x = fmaf(g[s], v.x, be[s]);
            r.y = fmaf(g[s], v.y, be[s]);
            r.z = fmaf(g[s], v.z, be[s]);
            r.w = fmaf(g[s], v.w, be[s]);
            __builtin_nontemporal_store(r, &ow[(size_t)s * 256 + i * 64 + lane]);
        }
    }
}

// ---------------------------------------------------------------------------
extern "C" void kernel_launch(void* const* d_in, const int* in_sizes, int n_in,
                              void* d_out, int out_size, void* d_ws, size_t ws_size,
                              hipStream_t stream)
{
    const float* x    = (const float*)d_in[0];
    const float* cond = (const float*)d_in[1];
    const float* W    = (const float*)d_in[2];
    const float* bias = (const float*)d_in[3];
    float* out    = (float*)d_out;
    float* params = (float*)d_ws;              // 131072 f32 = 512 KB

    params_kernel<<<512, THREADS, 0, stream>>>(cond, W, bias, params);
    stream_kernel<<<2048, THREADS, 0, stream>>>(x, params, out);
}

// Round 6
// 97.816 us; speedup vs baseline: 1.3449x; 1.0065x over previous
//
#include <hip/hip_runtime.h>

// SNN-FiLM v6 — two-kernel; streamer gets 128-VGPR budget (no spill) and a
// 3-ahead pipeline.
//   x:        [T=16, B=16, C=256, H=32, W=32]  f32  (256 MB)
//   condition:[T=16, B=16, Cc=256]             f32
//   W:        [2C=512, Cc=256]                 f32
//   b:        [512]                            f32
//   out = (gamma+1)*x + beta
//
// Kernel A (unchanged from v5): params[t*16+b][d]; gamma rows stored with
//   +1+bias baked in, beta rows with +bias. 512 blocks.
// Kernel B: 2048 blocks x 256 thr, __launch_bounds__(256,4) -> 128 VGPR cap.
//   Wave owns 8 slices (32 KB contiguous). 3-ahead fully-unrolled float4
//   pipeline (4 live slices = 64 buffer VGPRs), nontemporal both ways,
//   no LDS, no barriers, wave-uniform scalar gamma/beta loads.

#define T_STEPS 16
#define B_SZ    16
#define C_SZ    256
#define CC_SZ   256
#define HW      1024
#define THREADS 256

typedef float f4 __attribute__((ext_vector_type(4)));

__device__ __forceinline__ float qreduce(float v) {   // sum over 4-lane group
    v += __shfl_xor(v, 1);
    v += __shfl_xor(v, 2);
    return v;
}

// ---------------------------------------------------------------------------
// Kernel A — params
// ---------------------------------------------------------------------------
__global__ __launch_bounds__(THREADS)
void params_kernel(const float* __restrict__ cond,
                   const float* __restrict__ W,
                   const float* __restrict__ bias,
                   float* __restrict__ params)
{
    __shared__ f4 s_spk[CC_SZ];        // [cc] -> spikes for t = tg*4 .. tg*4+3

    const int bid = blockIdx.x;        // 0..511
    const int tg  = bid & 3;           // t-group (4 t's)
    const int dg  = (bid >> 2) & 7;    // d-group (64 rows)
    const int b   = bid >> 5;          // batch
    const int tid = threadIdx.x;

    // ---- LIF: one full 16-step chain per cc, record this block's 4 t's ----
    {
        const float* cp = cond + (size_t)b * CC_SZ + tid;
        float v = 0.0f;
        f4 rec = {0.f, 0.f, 0.f, 0.f};
#pragma unroll
        for (int t = 0; t < T_STEPS; ++t) {
            float xv = cp[(size_t)t * (B_SZ * CC_SZ)];
            v = v + (xv - v) * 0.5f;                  // charge (TAU=2)
            float s = (v >= 1.0f) ? 1.0f : 0.0f;      // fire
            v = (s != 0.0f) ? 0.0f : v;               // hard reset
            const bool mine = ((t >> 2) == tg);       // runtime pred, static dst
            if ((t & 3) == 0) rec.x = mine ? s : rec.x;
            if ((t & 3) == 1) rec.y = mine ? s : rec.y;
            if ((t & 3) == 2) rec.z = mine ? s : rec.z;
            if ((t & 3) == 3) rec.w = mine ? s : rec.w;
        }
        s_spk[tid] = rec;
    }
    __syncthreads();

    // ---- dots: row r = tid>>2 (64 rows), K-quarter q = tid&3, 4 t's --------
    {
        const int r = tid >> 2;
        const int q = tid & 3;
        const int d = dg * 64 + r;                    // 0..511
        const f4* Wr = reinterpret_cast<const f4*>(W + (size_t)d * CC_SZ)
                       + q * 16;
        const f4* sp = s_spk + q * 64;
        f4 acc = {0.f, 0.f, 0.f, 0.f};                // acc[j] for t = tg*4+j
#pragma unroll
        for (int k = 0; k < 16; ++k) {
            f4 w  = Wr[k];
            f4 s0 = sp[4 * k + 0];
            f4 s1 = sp[4 * k + 1];
            f4 s2 = sp[4 * k + 2];
            f4 s3 = sp[4 * k + 3];
            acc += w.x * s0 + w.y * s1 + w.z * s2 + w.w * s3;
        }
        acc.x = qreduce(acc.x);
        acc.y = qreduce(acc.y);
        acc.z = qreduce(acc.z);
        acc.w = qreduce(acc.w);
        if (q == 0) {
            const float add = bias[d] + ((d < C_SZ) ? 1.0f : 0.0f); // bake +1
            float vals[4] = {acc.x + add, acc.y + add, acc.z + add, acc.w + add};
#pragma unroll
            for (int j = 0; j < 4; ++j) {
                const int t = tg * 4 + j;
                params[((size_t)t * B_SZ + b) * 512 + d] = vals[j];
            }
        }
    }
}

// ---------------------------------------------------------------------------
// Kernel B — pure streamer (128-VGPR budget, 3-ahead pipeline)
// ---------------------------------------------------------------------------
__global__ __launch_bounds__(THREADS, 4)
void stream_kernel(const float* __restrict__ x,
                   const float* __restrict__ params,
                   float* __restrict__ out)
{
    const int bid  = blockIdx.x;           // 0..2047
    const int tb   = bid >> 3;             // t*16 + b
    const int cb   = (bid & 7) * 32;       // block's c base
    const int tid  = threadIdx.x;
    const int wid  = __builtin_amdgcn_readfirstlane(tid >> 6);  // wave 0..3
    const int lane = tid & 63;

    const size_t base = ((size_t)tb * C_SZ + cb + wid * 8) * HW;
    const f4* __restrict__ xw = reinterpret_cast<const f4*>(x + base);
    f4*       __restrict__ ow = reinterpret_cast<f4*>(out + base);

    // ---- prefetch slices 0..2 (12 loads in flight before any dependency) --
    f4 buf[8][4];
#pragma unroll
    for (int s = 0; s < 3; ++s)
#pragma unroll
        for (int i = 0; i < 4; ++i)
            buf[s][i] = __builtin_nontemporal_load(
                &xw[(size_t)s * 256 + i * 64 + lane]);

    // ---- gamma/beta: wave-uniform addresses -> scalar loads ----------------
    const float* pg = params + (size_t)tb * 512 + cb + wid * 8;  // gamma+1
    const float* pb = pg + C_SZ;                                 // beta
    float g[8], be[8];
#pragma unroll
    for (int i = 0; i < 8; ++i) { g[i] = pg[i]; be[i] = pb[i]; }

    // ---- fully-unrolled 3-ahead pipeline -----------------------------------
#pragma unroll
    for (int s = 0; s < 8; ++s) {
        if (s + 3 < 8) {
#pragma unroll
            for (int i = 0; i < 4; ++i)
                buf[s + 3][i] = __builtin_nontemporal_load(
                    &xw[(size_t)(s + 3) * 256 + i * 64 + lane]);
        }
#pragma unroll
        for (int i = 0; i < 4; ++i) {
            f4 v = buf[s][i];
            f4 r;
            r.x = fmaf(g[s], v.x, be[s]);
            r.y = fmaf(g[s], v.y, be[s]);
            r.z = fmaf(g[s], v.z, be[s]);
            r.w = fmaf(g[s], v.w, be[s]);
            __builtin_nontemporal_store(r, &ow[(size_t)s * 256 + i * 64 + lane]);
        }
    }
}

// ---------------------------------------------------------------------------
extern "C" void kernel_launch(void* const* d_in, const int* in_sizes, int n_in,
                              void* d_out, int out_size, void* d_ws, size_t ws_size,
                              hipStream_t stream)
{
    const float* x    = (const float*)d_in[0];
    const float* cond = (const float*)d_in[1];
    const float* W    = (const float*)d_in[2];
    const float* bias = (const float*)d_in[3];
    float* out    = (float*)d_out;
    float* params = (float*)d_ws;              // 131072 f32 = 512 KB

    params_kernel<<<512, THREADS, 0, stream>>>(cond, W, bias, params);
    stream_kernel<<<2048, THREADS, 0, stream>>>(x, params, out);
}